// Round 1
// baseline (197.646 us; speedup 1.0000x reference)
//
#include <hip/hip_runtime.h>

// Batched 14-qubit statevector simulator.
// One workgroup per batch sample; the full 2^14 complex64 state (128 KB)
// lives in LDS for the whole circuit. CNOTs are folded into GF(2) index
// remapping (no data movement); same-wire rotations are fused into single
// 2x2 complex gates: 56 LDS passes total.

#define NQ      14
#define NS      (1 << NQ)        // 16384 amplitudes
#define NT      512              // threads per block (8 waves)
#define NWAVES  (NT / 64)
#define NLAYERS 3
#define NGATES  (NQ + NLAYERS * NQ)   // 14 encoding + 42 layer gates = 56
#define PPT     ((NS / 2) / NT)  // amplitude pairs per thread = 16
#define APT     (NS / NT)        // amplitudes per thread = 32

struct c32 { float x, y; };
__device__ __forceinline__ c32 cmul(c32 a, c32 b) {
    return c32{ a.x * b.x - a.y * b.y, a.x * b.y + a.y * b.x };
}
__device__ __forceinline__ c32 cadd(c32 a, c32 b) { return c32{ a.x + b.x, a.y + b.y }; }

struct M2 { c32 a, b, c, d; };   // [[a, b], [c, d]]
__device__ __forceinline__ M2 mmul(M2 X, M2 Y) {
    M2 o;
    o.a = cadd(cmul(X.a, Y.a), cmul(X.b, Y.c));
    o.b = cadd(cmul(X.a, Y.b), cmul(X.b, Y.d));
    o.c = cadd(cmul(X.c, Y.a), cmul(X.d, Y.c));
    o.d = cadd(cmul(X.c, Y.b), cmul(X.d, Y.d));
    return o;
}
__device__ __forceinline__ M2 mRX(float c, float s) { return M2{ {c, 0.f}, {0.f, -s}, {0.f, -s}, {c, 0.f} }; }
__device__ __forceinline__ M2 mRY(float c, float s) { return M2{ {c, 0.f}, {-s, 0.f}, {s, 0.f},  {c, 0.f} }; }
__device__ __forceinline__ M2 mRZ(float c, float s) { return M2{ {c, -s},  {0.f, 0.f}, {0.f, 0.f}, {c, s} }; }

__global__ __launch_bounds__(NT)
void qsim_kernel(const float* __restrict__ z, const float* __restrict__ th,
                 float* __restrict__ out)
{
    extern __shared__ float2 st[];                 // 16384 x 8 B = 128 KB state
    __shared__ float    gmat[NGATES][8];           // fused 2x2 complex gates
    __shared__ unsigned marr[NGATES];              // pair mask  = col_q(M)
    __shared__ unsigned rarr[NGATES];              // parity row = row_q(M^-1)
    __shared__ unsigned frow[NQ];                  // final rows for <Z_w>
    __shared__ float    red[NWAVES][NQ];

    const int b   = blockIdx.x;
    const int tid = threadIdx.x;

    // ---- init |0...0> ----
    #pragma unroll
    for (int k = 0; k < APT; ++k) st[tid + k * NT] = make_float2(0.f, 0.f);
    if (tid == 0) st[0] = make_float2(1.f, 0.f);

    // ---- precompute fused gate matrices (one thread per gate) ----
    if (tid < NQ) {
        // encoding wire tid: RZ(z) * RY(z)
        float t = z[b * NQ + tid];
        float sn, cs; sincosf(0.5f * t, &sn, &cs);
        M2 m = mmul(mRZ(cs, sn), mRY(cs, sn));
        float* g = gmat[tid];
        g[0] = m.a.x; g[1] = m.a.y; g[2] = m.b.x; g[3] = m.b.y;
        g[4] = m.c.x; g[5] = m.c.y; g[6] = m.d.x; g[7] = m.d.y;
    } else if (tid < NGATES) {
        // layer gate: RZ(t2) * RY(t1) * RX(t0)
        int gi = tid - NQ;
        int l = gi / NQ, w = gi % NQ;
        const float* tp = th + (l * NQ + w) * 3;
        float s0, c0, s1, c1, s2, c2;
        sincosf(0.5f * tp[0], &s0, &c0);
        sincosf(0.5f * tp[1], &s1, &c1);
        sincosf(0.5f * tp[2], &s2, &c2);
        M2 m = mmul(mRZ(c2, s2), mmul(mRY(c1, s1), mRX(c0, s0)));
        float* g = gmat[tid];
        g[0] = m.a.x; g[1] = m.a.y; g[2] = m.b.x; g[3] = m.b.y;
        g[4] = m.c.x; g[5] = m.c.y; g[6] = m.d.x; g[7] = m.d.y;
    } else if (tid == NGATES) {
        // GF(2) mask schedule: CNOT(c,t) => cols[c]^=cols[t]; rows[t]^=rows[c]
        unsigned c[NQ], r[NQ];
        for (int w = 0; w < NQ; ++w) c[w] = r[w] = 1u << (NQ - 1 - w);
        for (int w = 0; w < NQ; ++w) { marr[w] = c[w]; rarr[w] = r[w]; }   // encoding (M = I)
        for (int l = 0; l < NLAYERS; ++l) {
            for (int w = 0; w < NQ; ++w) {
                marr[NQ + l * NQ + w] = c[w];
                rarr[NQ + l * NQ + w] = r[w];
            }
            // CNOT ring: (0,1)...(12,13),(13,0)
            for (int w = 0; w < NQ - 1; ++w) { c[w] ^= c[w + 1]; r[w + 1] ^= r[w]; }
            c[NQ - 1] ^= c[0]; r[0] ^= r[NQ - 1];
        }
        for (int w = 0; w < NQ; ++w) frow[w] = r[w];
    }
    __syncthreads();

    // ---- apply 56 fused gates, state resident in LDS ----
    for (int g = 0; g < NGATES; ++g) {
        const float* gm = gmat[g];
        const c32 Ma{ gm[0], gm[1] }, Mb{ gm[2], gm[3] };
        const c32 Mc{ gm[4], gm[5] }, Md{ gm[6], gm[7] };
        const unsigned m  = marr[g];
        const unsigned r  = rarr[g];
        const unsigned bp  = (unsigned)(__ffs(m) - 1);    // lowest set bit of pair mask
        const unsigned low = (1u << bp) - 1u;
        #pragma unroll 4
        for (int k = 0; k < PPT; ++k) {
            unsigned p = (unsigned)tid + (unsigned)(k * NT);
            unsigned y = ((p & ~low) << 1) | (p & low);    // bit bp == 0 representative
            if (__popc(y & r) & 1u) y ^= m;                // y := the x_q = 0 element
            unsigned y1 = y ^ m;
            float2 A = st[y], B = st[y1];
            c32 s0{ A.x, A.y }, s1{ B.x, B.y };
            c32 n0 = cadd(cmul(Ma, s0), cmul(Mb, s1));
            c32 n1 = cadd(cmul(Mc, s0), cmul(Md, s1));
            st[y]  = make_float2(n0.x, n0.y);
            st[y1] = make_float2(n1.x, n1.y);
        }
        __syncthreads();
    }

    // ---- expectations <Z_w> = sum_y |amp|^2 * (-1)^parity(y & frow[w]) ----
    unsigned fr[NQ];
    #pragma unroll
    for (int w = 0; w < NQ; ++w) fr[w] = frow[w];
    float ev[NQ];
    #pragma unroll
    for (int w = 0; w < NQ; ++w) ev[w] = 0.f;
    #pragma unroll 4
    for (int k = 0; k < APT; ++k) {
        unsigned y = (unsigned)tid + (unsigned)(k * NT);
        float2 A = st[y];
        float pr = A.x * A.x + A.y * A.y;
        #pragma unroll
        for (int w = 0; w < NQ; ++w)
            ev[w] += (__popc(y & fr[w]) & 1u) ? -pr : pr;
    }
    const int lane = tid & 63, wv = tid >> 6;
    #pragma unroll
    for (int w = 0; w < NQ; ++w) {
        float v = ev[w];
        #pragma unroll
        for (int off = 32; off > 0; off >>= 1) v += __shfl_down(v, off, 64);
        if (lane == 0) red[wv][w] = v;
    }
    __syncthreads();
    if (tid < NQ) {
        float v = 0.f;
        #pragma unroll
        for (int i = 0; i < NWAVES; ++i) v += red[i][tid];
        out[b * NQ + tid] = v;
    }
}

extern "C" void kernel_launch(void* const* d_in, const int* in_sizes, int n_in,
                              void* d_out, int out_size, void* d_ws, size_t ws_size,
                              hipStream_t stream)
{
    (void)n_in; (void)out_size; (void)d_ws; (void)ws_size;
    const float* z  = (const float*)d_in[0];   // (256, 14) float32
    const float* th = (const float*)d_in[1];   // (3, 14, 3) float32
    float* out = (float*)d_out;                // (256, 14) float32

    const int B = in_sizes[0] / NQ;            // 256 samples -> 256 blocks

    // 128 KB dynamic LDS (> 64 KB default cap) — idempotent, capture-safe
    hipFuncSetAttribute(reinterpret_cast<const void*>(qsim_kernel),
                        hipFuncAttributeMaxDynamicSharedMemorySize, NS * 8);

    qsim_kernel<<<dim3(B), dim3(NT), NS * 8, stream>>>(z, th, out);
}

// Round 2
// 134.094 us; speedup vs baseline: 1.4739x; 1.4739x over previous
//
#include <hip/hip_runtime.h>

// Batched 14-qubit statevector simulator, v2.
// - State (2^14 complex64 = 128 KB) lives in LDS per block (1 sample/block).
// - Encoding + layer-1 1q gates are folded into a product state (GF(2) map is
//   still identity there), built directly in registers.
// - Layers 2 and 3: gates grouped 5/5/4 wires per pass; each thread pulls one
//   coset of 32 (or 2x16) amplitudes into registers, applies the group's 2x2
//   gates in-register, writes back. CNOTs are compile-time GF(2) index algebra.
// - Readout via in-register 32-point Walsh-Hadamard transform.

#define NQ 14
#define NS (1 << NQ)
#define NT 512
#define NLAYERS 3

// ---------------- compile-time GF(2) schedule ----------------
struct Sched {
    unsigned m2[NQ], r2[NQ];   // masks/rows for layer-2 gates (after 1 CNOT ring)
    unsigned m3[NQ], r3[NQ];   // for layer-3 gates (after 2 rings)
    unsigned frow[NQ];         // readout rows (after 3 rings)
};

constexpr Sched make_sched() {
    Sched s{};
    unsigned c[NQ] = {}, r[NQ] = {};
    for (int w = 0; w < NQ; ++w) { c[w] = 1u << (NQ - 1 - w); r[w] = 1u << (NQ - 1 - w); }
    for (int ring = 0; ring < 3; ++ring) {
        // CNOT(w, w+1) for w=0..12, then CNOT(13, 0): cols[c]^=cols[t]; rows[t]^=rows[c]
        for (int w = 0; w < NQ - 1; ++w) { c[w] ^= c[w + 1]; r[w + 1] ^= r[w]; }
        c[NQ - 1] ^= c[0]; r[0] ^= r[NQ - 1];
        if (ring == 0) for (int w = 0; w < NQ; ++w) { s.m2[w] = c[w]; s.r2[w] = r[w]; }
        if (ring == 1) for (int w = 0; w < NQ; ++w) { s.m3[w] = c[w]; s.r3[w] = r[w]; }
        if (ring == 2) for (int w = 0; w < NQ; ++w) { s.frow[w] = r[w]; }
    }
    return s;
}
constexpr Sched S = make_sched();

struct Meta {
    unsigned mask[5];
    unsigned row[5];
    unsigned lut[32];   // lut[j] = XOR of mask[i] over set bits i of j
    unsigned npiv;      // non-pivot bit mask (complement basis positions)
    int K;              // wires in this pass (5 or 4)
    int g0;             // base index into gate-matrix table
};

constexpr Meta mkpass(const unsigned* m, const unsigned* r, int w0, int K, int g0base) {
    Meta p{};
    p.K = K; p.g0 = g0base + w0;
    for (int i = 0; i < K; ++i) { p.mask[i] = m[w0 + i]; p.row[i] = r[w0 + i]; }
    // Gaussian elimination, preferring HIGH pivot bits (so non-pivots — the
    // per-thread rep bits — occupy low bits => good LDS bank spread).
    unsigned red[5] = {}, pivbit[5] = {}, pivs = 0;
    for (int i = 0; i < K; ++i) {
        unsigned v = p.mask[i];
        for (int j = 0; j < i; ++j) if (v & pivbit[j]) v ^= red[j];
        unsigned hb = 0;
        for (int b = 13; b >= 0; --b) if ((v >> b) & 1u) { hb = 1u << b; break; }
        red[i] = v; pivbit[i] = hb; pivs |= hb;
    }
    p.npiv = (~pivs) & 0x3FFFu;
    for (int j = 0; j < (1 << K); ++j) {
        unsigned x = 0;
        for (int i = 0; i < K; ++i) if ((j >> i) & 1) x ^= p.mask[i];
        p.lut[j] = x;
    }
    return p;
}

constexpr Meta PM[6] = {
    mkpass(S.m2, S.r2, 0, 5, 0),  mkpass(S.m2, S.r2, 5, 5, 0),  mkpass(S.m2, S.r2, 10, 4, 0),
    mkpass(S.m3, S.r3, 0, 5, 14), mkpass(S.m3, S.r3, 5, 5, 14), mkpass(S.m3, S.r3, 10, 4, 14),
};
static_assert(__builtin_popcount(PM[0].npiv) == 9, "GE failed p0");
static_assert(__builtin_popcount(PM[2].npiv) == 10, "GE failed p2");
static_assert(__builtin_popcount(PM[5].npiv) == 10, "GE failed p5");

// ---------------- complex helpers ----------------
struct c32 { float x, y; };
__device__ __forceinline__ c32 cmul(c32 a, c32 b) {
    return c32{ a.x * b.x - a.y * b.y, a.x * b.y + a.y * b.x };
}
__device__ __forceinline__ c32 cadd(c32 a, c32 b) { return c32{ a.x + b.x, a.y + b.y }; }
__device__ __forceinline__ float2 cmulf(float2 a, float2 b) {
    return make_float2(a.x * b.x - a.y * b.y, a.x * b.y + a.y * b.x);
}

struct M2x2 { c32 a, b, c, d; };
__device__ __forceinline__ M2x2 mmul(M2x2 X, M2x2 Y) {
    M2x2 o;
    o.a = cadd(cmul(X.a, Y.a), cmul(X.b, Y.c));
    o.b = cadd(cmul(X.a, Y.b), cmul(X.b, Y.d));
    o.c = cadd(cmul(X.c, Y.a), cmul(X.d, Y.c));
    o.d = cadd(cmul(X.c, Y.b), cmul(X.d, Y.d));
    return o;
}
__device__ __forceinline__ M2x2 mRX(float c, float s) { return M2x2{ {c,0.f},{0.f,-s},{0.f,-s},{c,0.f} }; }
__device__ __forceinline__ M2x2 mRY(float c, float s) { return M2x2{ {c,0.f},{-s,0.f},{s,0.f},{c,0.f} }; }
__device__ __forceinline__ M2x2 mRZ(float c, float s) { return M2x2{ {c,-s},{0.f,0.f},{0.f,0.f},{c,s} }; }

// ---------------- one grouped gate pass ----------------
template<int P>
__device__ __forceinline__ void do_pass(float2* st, const float4* gm4, int tid) {
    constexpr Meta pm = PM[P];
    constexpr int K = pm.K;
    constexpr int NSLOT = 1 << K;
    constexpr int NCS = (K == 5) ? 1 : 2;

    #pragma unroll
    for (int cs = 0; cs < NCS; ++cs) {
        unsigned idx = (unsigned)tid + (unsigned)(cs << 9);
        // coset representative: deposit idx bits into non-pivot positions
        unsigned rep = 0;
        #pragma unroll
        for (int bb = 0; bb < 14; ++bb)
            if ((pm.npiv >> bb) & 1u)
                rep |= ((idx >> __builtin_popcount(pm.npiv & ((1u << bb) - 1))) & 1u) << bb;
        // lane-dependent offset within the coset (bank spread); linear in idx
        unsigned lt = 0;
        #pragma unroll
        for (int i = 0; i < K; ++i) lt ^= ((idx >> i) & 1u) ? pm.mask[i] : 0u;
        const unsigned repf = rep ^ lt;
        // role-parity per gate: selects normal vs swapped matrix variant
        unsigned sel[5];
        #pragma unroll
        for (int i = 0; i < K; ++i) sel[i] = __popc(repf & pm.row[i]) & 1u;

        float2 e[NSLOT];
        #pragma unroll
        for (int j = 0; j < NSLOT; ++j) e[j] = st[repf ^ pm.lut[j]];

        #pragma unroll
        for (int w = 0; w < K; ++w) {
            const float4* mp = gm4 + (((unsigned)(pm.g0 + w) * 2u + sel[w]) * 2u);
            const float4 R0 = mp[0];   // (A.re, A.im, B.re, B.im)
            const float4 R1 = mp[1];   // (C.re, C.im, D.re, D.im)
            #pragma unroll
            for (int t = 0; t < NSLOT / 2; ++t) {
                const int j  = ((t >> w) << (w + 1)) | (t & ((1 << w) - 1));
                const int j2 = j | (1 << w);
                const float2 x = e[j], y = e[j2];
                e[j]  = make_float2(R0.x * x.x - R0.y * x.y + R0.z * y.x - R0.w * y.y,
                                    R0.x * x.y + R0.y * x.x + R0.z * y.y + R0.w * y.x);
                e[j2] = make_float2(R1.x * x.x - R1.y * x.y + R1.z * y.x - R1.w * y.y,
                                    R1.x * x.y + R1.y * x.x + R1.z * y.y + R1.w * y.x);
            }
        }
        #pragma unroll
        for (int j = 0; j < NSLOT; ++j) st[repf ^ pm.lut[j]] = e[j];
    }
}

__global__ __launch_bounds__(NT, 2)
void qsim_kernel(const float* __restrict__ z, const float* __restrict__ th,
                 float* __restrict__ out)
{
    extern __shared__ float2 st[];            // 16384 x 8 B state
    __shared__ float4 gm4[28 * 4];            // [gate 0..27][variant 0/1][2x float4]
    __shared__ float2 vtab[NQ][2];            // per-wire (encoding x layer-1) |psi_w>
    __shared__ float  red[NT / 64][NQ];

    const int bq  = blockIdx.x;
    const int tid = threadIdx.x;

    // ---- metadata: fused gate matrices + per-wire product vectors ----
    if (tid < 28) {
        const int rd = tid / 14, w = tid % 14, l = rd + 1;   // theta layers 1,2
        const float* tp = th + (l * NQ + w) * 3;
        float s0, c0, s1, c1, s2, c2;
        __sincosf(0.5f * tp[0], &s0, &c0);
        __sincosf(0.5f * tp[1], &s1, &c1);
        __sincosf(0.5f * tp[2], &s2, &c2);
        const M2x2 G = mmul(mRZ(c2, s2), mmul(mRY(c1, s1), mRX(c0, s0)));
        gm4[tid * 4 + 0] = make_float4(G.a.x, G.a.y, G.b.x, G.b.y);
        gm4[tid * 4 + 1] = make_float4(G.c.x, G.c.y, G.d.x, G.d.y);
        gm4[tid * 4 + 2] = make_float4(G.d.x, G.d.y, G.c.x, G.c.y);  // swapped variant
        gm4[tid * 4 + 3] = make_float4(G.b.x, G.b.y, G.a.x, G.a.y);
    } else if (tid >= 32 && tid < 32 + NQ) {
        const int w = tid - 32;
        const float zt = z[bq * NQ + w];
        float sz_, cz_; __sincosf(0.5f * zt, &sz_, &cz_);
        // (RZ(z)*RY(z)) |0> = (cos*e^{-iz/2}, sin*e^{+iz/2})
        const c32 a0{ cz_ * cz_, -cz_ * sz_ }, b0{ sz_ * cz_, sz_ * sz_ };
        const float* tp = th + (0 * NQ + w) * 3;
        float s0, c0, s1, c1, s2, c2;
        __sincosf(0.5f * tp[0], &s0, &c0);
        __sincosf(0.5f * tp[1], &s1, &c1);
        __sincosf(0.5f * tp[2], &s2, &c2);
        const M2x2 G = mmul(mRZ(c2, s2), mmul(mRY(c1, s1), mRX(c0, s0)));
        const c32 v0 = cadd(cmul(G.a, a0), cmul(G.b, b0));
        const c32 v1 = cadd(cmul(G.c, a0), cmul(G.d, b0));
        vtab[w][0] = make_float2(v0.x, v0.y);
        vtab[w][1] = make_float2(v1.x, v1.y);
    }
    __syncthreads();

    // ---- init: product state (encoding + layer-1 folded), strided layout ----
    {
        // y = tid + j*512 ; y bit p (p<9) from tid => wire 13-p ; j bit b => wire 4-b
        float2 pf = vtab[13][tid & 1];
        #pragma unroll
        for (int p = 1; p < 9; ++p) pf = cmulf(pf, vtab[13 - p][(tid >> p) & 1]);
        float2 e[32];
        e[0] = pf;
        #pragma unroll
        for (int bb = 0; bb < 5; ++bb) {
            const float2 v0 = vtab[4 - bb][0], v1 = vtab[4 - bb][1];
            #pragma unroll
            for (int t = 0; t < (1 << bb); ++t) {
                const float2 base = e[t];
                e[t + (1 << bb)] = cmulf(base, v1);
                e[t] = cmulf(base, v0);
            }
        }
        #pragma unroll
        for (int j = 0; j < 32; ++j) st[tid + (j << 9)] = e[j];
    }
    __syncthreads();

    // ---- 6 grouped gate passes (layers 2 and 3) ----
    do_pass<0>(st, gm4, tid); __syncthreads();
    do_pass<1>(st, gm4, tid); __syncthreads();
    do_pass<2>(st, gm4, tid); __syncthreads();
    do_pass<3>(st, gm4, tid); __syncthreads();
    do_pass<4>(st, gm4, tid); __syncthreads();
    do_pass<5>(st, gm4, tid); __syncthreads();

    // ---- readout: |amp|^2, in-register WHT over the 5 high bits ----
    float W[32];
    #pragma unroll
    for (int j = 0; j < 32; ++j) {
        const float2 a = st[tid + (j << 9)];
        W[j] = a.x * a.x + a.y * a.y;
    }
    #pragma unroll
    for (int bb = 0; bb < 5; ++bb) {
        #pragma unroll
        for (int t = 0; t < 16; ++t) {
            const int j  = ((t >> bb) << (bb + 1)) | (t & ((1 << bb) - 1));
            const int j2 = j | (1 << bb);
            const float u = W[j], v = W[j2];
            W[j] = u + v; W[j2] = u - v;
        }
    }
    float ev[NQ];
    #pragma unroll
    for (int w = 0; w < NQ; ++w) {
        const float val = W[S.frow[w] >> 9];
        ev[w] = (__popc((unsigned)tid & (S.frow[w] & 0x1FFu)) & 1) ? -val : val;
    }
    const int lane = tid & 63, wv = tid >> 6;
    #pragma unroll
    for (int w = 0; w < NQ; ++w) {
        float v = ev[w];
        #pragma unroll
        for (int off = 32; off > 0; off >>= 1) v += __shfl_down(v, off, 64);
        if (lane == 0) red[wv][w] = v;
    }
    __syncthreads();
    if (tid < NQ) {
        float v = 0.f;
        #pragma unroll
        for (int i = 0; i < NT / 64; ++i) v += red[i][tid];
        out[bq * NQ + tid] = v;
    }
}

extern "C" void kernel_launch(void* const* d_in, const int* in_sizes, int n_in,
                              void* d_out, int out_size, void* d_ws, size_t ws_size,
                              hipStream_t stream)
{
    (void)n_in; (void)out_size; (void)d_ws; (void)ws_size;
    const float* z  = (const float*)d_in[0];   // (256, 14) float32
    const float* th = (const float*)d_in[1];   // (3, 14, 3) float32
    float* out = (float*)d_out;                // (256, 14) float32

    const int B = in_sizes[0] / NQ;

    hipFuncSetAttribute(reinterpret_cast<const void*>(qsim_kernel),
                        hipFuncAttributeMaxDynamicSharedMemorySize, NS * 8);

    qsim_kernel<<<dim3(B), dim3(NT), NS * 8, stream>>>(z, th, out);
}